// Round 9
// baseline (90.415 us; speedup 1.0000x reference)
//
#include <hip/hip_runtime.h>
#include <hip/hip_bf16.h>

#define NN 4096      // N = 2*B
#define BB 2048      // B
#define DD 512       // D
#define TM 64        // C tile (R9: 64x64, one wave per block, NO LDS)
#define NTILE (NN/TM)                 // 64
#define NPAIR (NTILE*(NTILE+1)/2)     // 2080 blocks: bi <= bj
#define NKQ (DD/8)                    // 64 k-chunks of 8 bf16 (16 B)

typedef __bf16 bf16x8 __attribute__((ext_vector_type(8)));
typedef float  f32x4  __attribute__((ext_vector_type(4)));

__device__ __forceinline__ unsigned short f2bf(float x) {
    unsigned int u = __float_as_uint(x);
    unsigned int r = (u + 0x7fffu + ((u >> 16) & 1u)) >> 16;  // RNE; inputs finite
    return (unsigned short)r;
}

// ---------------------------------------------------------------------------
// Kernel A: row-normalize z = [z_i; z_j] -> bf16 in K-CHUNK-TRANSPOSED layout
//   zn_t[kq][n]  (kq = k/8, entry = 16 B = 8 bf16 of row n, k = kq*8..kq*8+7)
// so MFMA fragment loads in kernel B are COALESCED direct-from-global
// (16 consecutive lanes -> 16 consecutive 16 B entries). Lane == kq here.
// Also zero-inits rowsum[] and out[0] (stream order).
// ---------------------------------------------------------------------------
__global__ __launch_bounds__(256) void normalize_kernel(
        const float* __restrict__ z_i, const float* __restrict__ z_j,
        unsigned short* __restrict__ zn, float* __restrict__ rowsum,
        float* __restrict__ out) {
    if (threadIdx.x < 4) rowsum[blockIdx.x * 4 + threadIdx.x] = 0.f;
    if (blockIdx.x == 0 && threadIdx.x == 0) out[0] = 0.f;

    int row  = blockIdx.x * 4 + (threadIdx.x >> 6);
    int lane = threadIdx.x & 63;          // == k-chunk kq
    const float* src = (row < BB) ? (z_i + (size_t)row * DD)
                                  : (z_j + (size_t)(row - BB) * DD);
    const float4* s4 = (const float4*)src;
    float4 v0 = s4[lane * 2 + 0];
    float4 v1 = s4[lane * 2 + 1];
    float ss = v0.x*v0.x + v0.y*v0.y + v0.z*v0.z + v0.w*v0.w
             + v1.x*v1.x + v1.y*v1.y + v1.z*v1.z + v1.w*v1.w;
    #pragma unroll
    for (int off = 1; off < 64; off <<= 1) ss += __shfl_xor(ss, off, 64);
    float inv = 1.0f / fmaxf(sqrtf(ss), 1e-8f);

    float f[8] = {v0.x, v0.y, v0.z, v0.w, v1.x, v1.y, v1.z, v1.w};
    unsigned int p[4];
    #pragma unroll
    for (int k = 0; k < 4; ++k) {
        unsigned int lo = f2bf(f[2*k] * inv);
        unsigned int hi = f2bf(f[2*k+1] * inv);
        p[k] = lo | (hi << 16);
    }
    uint4 outv = make_uint4(p[0], p[1], p[2], p[3]);
    // transposed store: entry (kq=lane, n=row)
    *(uint4*)(zn + ((size_t)lane * NN + row) * 8) = outv;
}

// ---------------------------------------------------------------------------
// Kernel B (R9): sim = (zn @ zn^T) * 2, upper-triangular 64x64 tiles,
// ONE WAVE PER BLOCK (2080 blocks), ZERO LDS / ZERO barriers.
// Rationale: R1/R7/R8 pipelining all neutral -> LDS round-trip itself
// (stage 270 MB in + ds_read 270 MB out + barrier coupling) is the cost,
// not its latency. zn is 4 MB = L2-resident; with the k-chunk-transposed
// layout a fragment load is global_load_dwordx4 with 16 consecutive lanes
// hitting 16 consecutive 16 B entries (256 B segments) — coalesced, unlike
// R6's 1 KB-stride row-gather. Operands flow L2 -> VGPR directly.
// 2080 blocks ~ 8.1 waves/CU (tail 1.6% vs R5's 50% second-round tail).
// Epilogue unchanged: atomic rowsum (R1-R4 A/B), selfsim (diag),
// possim (bj == bi+32).
// ---------------------------------------------------------------------------
__global__ __launch_bounds__(64) void simexp_kernel(
        const unsigned short* __restrict__ zn, float* __restrict__ rowsum,
        float* __restrict__ selfsim, float* __restrict__ possim) {
    // triangular decode: p -> (bi <= bj)
    int p  = blockIdx.x;
    int bj = (int)((sqrtf(8.0f * (float)p + 1.0f) - 1.0f) * 0.5f);
    while ((bj + 1) * (bj + 2) / 2 <= p) ++bj;
    while (bj * (bj + 1) / 2 > p) --bj;
    int bi = p - bj * (bj + 1) / 2;
    const bool diag = (bi == bj);

    const int tid  = threadIdx.x;            // 0..63 — one wave
    const int lrow = tid & 15, quad = tid >> 4;

    f32x4 acc[4][4];
    #pragma unroll
    for (int i = 0; i < 4; ++i)
        #pragma unroll
        for (int j = 0; j < 4; ++j) acc[i][j] = (f32x4){0.f, 0.f, 0.f, 0.f};

    // K loop: 16 steps of K=32; fragment k-chunk = s*4 + quad (same lane
    // mapping verified by the previous LDS kernels' swizzled reads).
    #pragma unroll
    for (int s = 0; s < DD / 32; ++s) {
        const unsigned short* kbase = zn + ((size_t)(s * 4 + quad) * NN) * 8;
        bf16x8 a[4], b[4];
        #pragma unroll
        for (int ti = 0; ti < 4; ++ti)
            a[ti] = *(const bf16x8*)(kbase + (size_t)(bi * TM + ti * 16 + lrow) * 8);
        #pragma unroll
        for (int tj = 0; tj < 4; ++tj)
            b[tj] = *(const bf16x8*)(kbase + (size_t)(bj * TM + tj * 16 + lrow) * 8);
        #pragma unroll
        for (int ti = 0; ti < 4; ++ti)
            #pragma unroll
            for (int tj = 0; tj < 4; ++tj)
                acc[ti][tj] = __builtin_amdgcn_mfma_f32_16x16x32_bf16(
                    a[ti], b[tj], acc[ti][tj], 0, 0, 0);
    }

    // Epilogue. C/D layout (verified): tile row = ti*16 + quad*4 + reg,
    // tile col = tj*16 + lrow.
    float rowpart[4][4];   // [ti][reg]
    float colpart[4];      // [tj]
    #pragma unroll
    for (int i = 0; i < 4; ++i) {
        colpart[i] = 0.f;
        #pragma unroll
        for (int r = 0; r < 4; ++r) rowpart[i][r] = 0.f;
    }
    #pragma unroll
    for (int ti = 0; ti < 4; ++ti)
        #pragma unroll
        for (int tj = 0; tj < 4; ++tj)
            #pragma unroll
            for (int reg = 0; reg < 4; ++reg) {
                float e = __expf(acc[ti][tj][reg] * 2.0f);
                rowpart[ti][reg] += e;
                colpart[tj]      += e;
            }

    // row-sums: reduce over lrow (16-lane groups)
    #pragma unroll
    for (int ti = 0; ti < 4; ++ti) {
        #pragma unroll
        for (int reg = 0; reg < 4; ++reg) {
            float v = rowpart[ti][reg];
            v += __shfl_xor(v, 1, 64);
            v += __shfl_xor(v, 2, 64);
            v += __shfl_xor(v, 4, 64);
            v += __shfl_xor(v, 8, 64);
            if (lrow == 0)
                atomicAdd(&rowsum[bi * TM + ti * 16 + quad * 4 + reg], v);
        }
    }
    // col-sums -> rows of bj tile (transpose); skip on diagonal tiles
    if (!diag) {
        #pragma unroll
        for (int tj = 0; tj < 4; ++tj) {
            float v = colpart[tj];
            v += __shfl_xor(v, 16, 64);
            v += __shfl_xor(v, 32, 64);
            if (quad == 0)
                atomicAdd(&rowsum[bj * TM + tj * 16 + lrow], v);
        }
    }

    // tile-diagonal extraction: lanes with lrow>>2==quad hold element (r,r)
    // of the tile at acc[ti][ti][lrow&3], r = ti*16 + lrow.
    const bool posb = (bj == bi + NTILE / 2);   // bj == bi + 32  (col offset B)
    if ((diag || posb) && (lrow >> 2) == quad) {
        #pragma unroll
        for (int ti = 0; ti < 4; ++ti) {
            float v = 2.0f * acc[ti][ti][lrow & 3];
            int R = bi * TM + ti * 16 + lrow;
            if (diag) {
                selfsim[R] = v;
            } else {
                possim[R]      = v;   // sim[r][r+B]
                possim[R + BB] = v;   // == sim[r+B][r]
            }
        }
    }
}

// ---------------------------------------------------------------------------
// Kernel C: loss_r = log(rowsum_r - exp(selfsim_r)) - possim_r; block-reduce;
// atomicAdd(out, sum/N). 3 float reads per row — no zn traffic.
// ---------------------------------------------------------------------------
__global__ __launch_bounds__(256) void rowfinal_kernel(
        const float* __restrict__ rowsum, const float* __restrict__ selfsim,
        const float* __restrict__ possim, float* __restrict__ out) {
    __shared__ float s[256];
    int r = blockIdx.x * 256 + threadIdx.x;
    s[threadIdx.x] = logf(rowsum[r] - __expf(selfsim[r])) - possim[r];
    __syncthreads();
    #pragma unroll
    for (int off = 128; off > 0; off >>= 1) {
        if (threadIdx.x < off) s[threadIdx.x] += s[threadIdx.x + off];
        __syncthreads();
    }
    if (threadIdx.x == 0) atomicAdd(out, s[0] * (1.0f / (float)NN));
}

extern "C" void kernel_launch(void* const* d_in, const int* in_sizes, int n_in,
                              void* d_out, int out_size, void* d_ws, size_t ws_size,
                              hipStream_t stream) {
    const float* z_i = (const float*)d_in[0];
    const float* z_j = (const float*)d_in[1];
    float* out = (float*)d_out;

    unsigned short* zn = (unsigned short*)d_ws;                    // 4 MB (zn_t)
    float* rowsum  = (float*)((char*)d_ws + (size_t)NN * DD * 2);  // N floats
    float* selfsim = rowsum + NN;                                  // N floats
    float* possim  = selfsim + NN;                                 // N floats

    normalize_kernel<<<NN / 4, 256, 0, stream>>>(z_i, z_j, zn, rowsum, out);
    simexp_kernel<<<NPAIR, 64, 0, stream>>>(zn, rowsum, selfsim, possim);
    rowfinal_kernel<<<NN / 256, 256, 0, stream>>>(rowsum, selfsim, possim, out);
}